// Round 5
// baseline (4750.346 us; speedup 1.0000x reference)
//
#include <hip/hip_runtime.h>
#include <hip/hip_bf16.h>
#include <stdint.h>

// ---------------------------------------------------------------------------
// BiLSTM (H=256, fwd+rev) -> sentence LSTM (512->512) -> linear -> CRF(16)
// Round 11: per-wave flag handoff (R4) with compact flag lines.
//   - Each wave = one sync unit: h slice store (8B agent atomics) then lane-0
//     RELEASE flag store (waitcnt drains the wave's stores). No __syncthreads
//     in the step loop.
//   - Flags are COMPACT: one uint per wave, consecutive within a group, so a
//     consumer's poll round is 1-2 coalesced 128B L3 requests (R4 used one
//     128B line per flag -> poll storm; suspected cause of the R4 hang).
//   - s_sleep(2) poll cadence (R0-proven).
//   - h data loaded exactly once, after the flag confirms (poll-cheap,
//     load-once — the R1/R3 lesson).
//   - h_cat scatter store after the flag release (off the drain path).
//   - 2-parity hb rotation; invariant: flag(t) implies the wave finished
//     reading h(t-1), so overwriting parity (t+1)&1 is safe.
// ---------------------------------------------------------------------------

typedef __bf16 bf16_t;
typedef __bf16 bf16x8 __attribute__((ext_vector_type(8)));
typedef __bf16 bf16x4v __attribute__((ext_vector_type(4)));
typedef float f32x4 __attribute__((ext_vector_type(4)));
typedef unsigned long long u64;

#define MFMA_BF16(a, b, c) __builtin_amdgcn_mfma_f32_16x16x32_bf16((a), (b), (c), 0, 0, 0)

__device__ __forceinline__ float sigm_(float x) { return 1.f / (1.f + __expf(-x)); }
__device__ __forceinline__ float tanh_(float x) {
  x = fminf(20.f, fmaxf(-20.f, x));
  float e = __expf(-2.f * x);
  return (1.f - e) / (1.f + e);
}

__device__ __forceinline__ u64 aload8(const u64* p) {
  return __hip_atomic_load(p, __ATOMIC_RELAXED, __HIP_MEMORY_SCOPE_AGENT);
}
__device__ __forceinline__ void astore8(u64* p, u64 v) {
  __hip_atomic_store(p, v, __ATOMIC_RELAXED, __HIP_MEMORY_SCOPE_AGENT);
}

union U16 { struct { unsigned long long a, b; } s; bf16x8 v; };
union U8  { bf16x4v v; unsigned long long u; };

// zero flag region each launch
__global__ void zero8(u64* __restrict__ p, int n) {
  int i = blockIdx.x * 256 + threadIdx.x;
  int s = gridDim.x * 256;
  for (; i < n; i += s) p[i] = 0ull;
}

// ---------------------------- fp32 -> bf16 convert -------------------------
__global__ void cvt4(const float* __restrict__ in, bf16_t* __restrict__ out, int n4) {
  int i = blockIdx.x * blockDim.x + threadIdx.x;
  int stride = gridDim.x * blockDim.x;
  for (; i < n4; i += stride) {
    float4 v = ((const float4*)in)[i];
    bf16x4v o;
    o.x = (bf16_t)v.x; o.y = (bf16_t)v.y; o.z = (bf16_t)v.z; o.w = (bf16_t)v.w;
    ((bf16x4v*)out)[i] = o;
  }
}

// ------------------------------- bf16 GEMM ---------------------------------
__global__ void __launch_bounds__(256, 2)
gemm_bt(const bf16_t* __restrict__ A, const bf16_t* __restrict__ B,
        bf16_t* __restrict__ C, int M, int N, int K) {
  const int tid = threadIdx.x;
  const int w = tid >> 6, lane = tid & 63, quad = lane >> 4, l15 = lane & 15;
  const int ntiles = N >> 7;
  const int m0 = (blockIdx.x / ntiles) << 7;
  const int n0 = (blockIdx.x % ntiles) << 7;
  const int wm = (w >> 1) << 6, wn = (w & 1) << 6;

  __shared__ bf16_t As[128 * 72];
  __shared__ bf16_t Bs[128 * 72];

  const f32x4 z4 = {0.f, 0.f, 0.f, 0.f};
  f32x4 acc[4][4];
#pragma unroll
  for (int i = 0; i < 4; ++i)
#pragma unroll
    for (int j = 0; j < 4; ++j) acc[i][j] = z4;

  const int nk = K >> 6;
  for (int kt = 0; kt < nk; ++kt) {
    uint4 av[4], bv[4];
#pragma unroll
    for (int i = 0; i < 4; ++i) {
      int cid = tid + i * 256;
      int r = cid >> 3, c = cid & 7;
      av[i] = *(const uint4*)&A[(size_t)(m0 + r) * K + kt * 64 + c * 8];
      bv[i] = *(const uint4*)&B[(size_t)(n0 + r) * K + kt * 64 + c * 8];
    }
    __syncthreads();
#pragma unroll
    for (int i = 0; i < 4; ++i) {
      int cid = tid + i * 256;
      int r = cid >> 3, c = cid & 7;
      *(uint4*)&As[r * 72 + c * 8] = av[i];
      *(uint4*)&Bs[r * 72 + c * 8] = bv[i];
    }
    __syncthreads();
#pragma unroll
    for (int s = 0; s < 2; ++s) {
      bf16x8 af[4], bfr[4];
#pragma unroll
      for (int i = 0; i < 4; ++i)
        af[i] = *(const bf16x8*)&As[(wm + i * 16 + l15) * 72 + s * 32 + quad * 8];
#pragma unroll
      for (int j = 0; j < 4; ++j)
        bfr[j] = *(const bf16x8*)&Bs[(wn + j * 16 + l15) * 72 + s * 32 + quad * 8];
#pragma unroll
      for (int i = 0; i < 4; ++i)
#pragma unroll
        for (int j = 0; j < 4; ++j)
          acc[i][j] = MFMA_BF16(af[i], bfr[j], acc[i][j]);
    }
  }
#pragma unroll
  for (int i = 0; i < 4; ++i)
#pragma unroll
    for (int j = 0; j < 4; ++j)
#pragma unroll
      for (int p = 0; p < 4; ++p) {
        int row = m0 + wm + i * 16 + quad * 4 + p;
        int col = n0 + wn + j * 16 + l15;
        C[(size_t)row * N + col] = (bf16_t)acc[i][j][p];
      }
}

// ----------------------- fwd/rev LSTM recurrence ---------------------------
// 128 blocks. grp = blockIdx&31 (dir*16+bg), hsp = blockIdx>>5 — group
// members share blockIdx%8 (XCD co-location heuristic; correctness-neutral).
// Flags: COMPACT, flags[grp*32 + (hsp*4+w)] (16 used + 16 pad per group).
// hb: [par(2)][dir(2)][256 rows][256 hid] bf16, 2-parity rotation.
__global__ void __launch_bounds__(256, 1)
lstm_fr(const bf16_t* __restrict__ gx, const bf16_t* __restrict__ whh,
        const float* __restrict__ b_f, const float* __restrict__ b_r,
        bf16_t* __restrict__ h_cat, bf16_t* __restrict__ hb,
        unsigned* __restrict__ flags) {
  const int tid = threadIdx.x;
  const int w = tid >> 6, lane = tid & 63, quad = lane >> 4, l15 = lane & 15;
  const int grp = blockIdx.x & 31;
  const int hsp = blockIdx.x >> 5;
  const int dir = grp >> 4;
  const int bg = grp & 15;
  const int rows0 = bg << 4;
  const int hid0 = hsp << 6;
  unsigned* fgrp = flags + grp * 32;          // 16 used uints, 16 pad
  unsigned* fmine = fgrp + (hsp * 4 + w);

  __shared__ bf16_t Ws[256 * 264];   // packed row = g*64+hh, K=256 (+8 pad)
  const bf16_t* Wg = whh + (size_t)dir * 262144;
#pragma unroll
  for (int i = 0; i < 32; ++i) {
    int id = tid + i * 256;          // 8192 = 256 rows x 32 chunks(16B)
    int r = id >> 5, c = id & 31;
    int g = r >> 6, hh = r & 63;
    *(uint4*)&Ws[r * 264 + c * 8] =
        *(const uint4*)&Wg[(size_t)(g * 256 + hid0 + hh) * 256 + c * 8];
  }
  const float* bias = dir ? b_r : b_f;
  const int hid = hid0 + w * 16 + quad * 4;   // 4 consecutive hid per lane
  float br[4][4];
#pragma unroll
  for (int g = 0; g < 4; ++g)
#pragma unroll
    for (int p = 0; p < 4; ++p) br[g][p] = bias[g * 256 + hid + p];
  const int brow = rows0 + l15;
  float c4[4] = {0.f, 0.f, 0.f, 0.f};
  const f32x4 z4 = {0.f, 0.f, 0.f, 0.f};
  __syncthreads();   // Ws ready (only barrier in the kernel)

  for (int t = 1; t <= 128; ++t) {
    const int tt = dir ? (128 - t) : (t - 1);
    // gate prefetch — issued before the poll, overlaps the wait
    const size_t gbase = ((size_t)brow * 128 + tt) * 2048 + (size_t)dir * 1024;
    bf16x4v gp[4];
#pragma unroll
    for (int g = 0; g < 4; ++g) gp[g] = *(const bf16x4v*)&gx[gbase + g * 256 + hid];

    f32x4 acc[4];
#pragma unroll
    for (int g = 0; g < 4; ++g) acc[g] = z4;

    if (t >= 2) {
      const unsigned tgt = (unsigned)(t - 1);
      for (;;) {
        unsigned f = tgt;
        if (lane < 16)   // 16 consecutive uints -> ONE 64B L3 request
          f = __hip_atomic_load(fgrp + lane, __ATOMIC_RELAXED, __HIP_MEMORY_SCOPE_AGENT);
        if (__all((int)(f >= tgt))) break;
        __builtin_amdgcn_s_sleep(2);
      }
      __asm__ __volatile__("" ::: "memory");
      const u64* hrow = (const u64*)
          (hb + (((size_t)((t & 1) ^ 1) * 2 + dir) * 256 + brow) * 256);
#pragma unroll
      for (int ks = 0; ks < 8; ++ks) {
        U16 u;
        u.s.a = aload8(hrow + ks * 8 + quad * 2);
        u.s.b = aload8(hrow + ks * 8 + quad * 2 + 1);
#pragma unroll
        for (int g = 0; g < 4; ++g) {
          bf16x8 af = *(const bf16x8*)&Ws[(g * 64 + w * 16 + l15) * 264 + ks * 32 + quad * 8];
          acc[g] = MFMA_BF16(af, u.v, acc[g]);
        }
      }
    }
    // epilogue: lane holds all 4 gates for (batch=brow, hid..hid+3)
    bf16x4v hv;
#pragma unroll
    for (int p = 0; p < 4; ++p) {
      float Pi = acc[0][p] + (float)gp[0][p] + br[0][p];
      float Pf = acc[1][p] + (float)gp[1][p] + br[1][p];
      float Pg = acc[2][p] + (float)gp[2][p] + br[2][p];
      float Po = acc[3][p] + (float)gp[3][p] + br[3][p];
      float cc = sigm_(Pf) * c4[p] + sigm_(Pi) * tanh_(Pg);
      c4[p] = cc;
      hv[p] = (bf16_t)(sigm_(Po) * tanh_(cc));
    }
    if (t < 128) {
      U8 cv; cv.v = hv;
      astore8((u64*)(hb + (((size_t)(t & 1) * 2 + dir) * 256 + brow) * 256 + hid), cv.u);
      // RELEASE: waitcnt drains this wave's h stores (vmcnt is wave-wide),
      // then the flag becomes visible. Single writer per uint.
      if (lane == 0)
        __hip_atomic_store(fmine, (unsigned)t, __ATOMIC_RELEASE, __HIP_MEMORY_SCOPE_AGENT);
    }
    // h_cat scatter store AFTER the flag — off the critical drain path
    *(bf16x4v*)&h_cat[((size_t)brow * 128 + tt) * 512 + dir * 256 + hid] = hv;
  }
}

// ------------------------ sentence LSTM recurrence -------------------------
// 128 blocks. bg = blockIdx&7 (XCD co-location), hsp = blockIdx>>3.
// Flags: COMPACT, flags[bg*64 + (hsp*4+w)] (64 uints = 256B per group).
// Consumer wave (batch-half nt) polls the 32 uints with w&1==nt.
// hb: [par(2)][256 rows][512 hid] bf16.
__global__ void __launch_bounds__(256, 1)
lstm_s(const bf16_t* __restrict__ gs, const bf16_t* __restrict__ wsh,
       const float* __restrict__ b_s, float* __restrict__ hT,
       bf16_t* __restrict__ hb, unsigned* __restrict__ flags) {
  const int tid = threadIdx.x;
  const int w = tid >> 6, lane = tid & 63, quad = lane >> 4, l15 = lane & 15;
  const int bg = blockIdx.x & 7;
  const int hsp = blockIdx.x >> 3;
  const int rows0 = bg << 5;
  const int hid0 = hsp << 5;
  const int nt = w & 1, hb2 = w >> 1;         // wave: batch-half, hid-half
  unsigned* fgrp = flags + bg * 64;           // 64 uints = 256B per group
  unsigned* fmine = fgrp + (hsp * 4 + w);
  // poll uint for lane<32: hsp_=lane>>1, w'=(lane&1)*2+nt  (w'&1==nt)
  const int pline = ((lane >> 1) << 2) | ((lane & 1) << 1) | nt;

  __shared__ bf16_t Ws[128 * 520];   // packed row = g*32+hh, K=512 (+8 pad)
#pragma unroll
  for (int i = 0; i < 32; ++i) {
    int id = tid + i * 256;          // 8192 = 128 rows x 64 chunks(16B)
    int r = id >> 6, c = id & 63;
    int g = r >> 5, hh = r & 31;
    *(uint4*)&Ws[r * 520 + c * 8] =
        *(const uint4*)&wsh[(size_t)(g * 512 + hid0 + hh) * 512 + c * 8];
  }
  const int hid = hid0 + hb2 * 16 + quad * 4;
  float br[4][4];
#pragma unroll
  for (int g = 0; g < 4; ++g)
#pragma unroll
    for (int p = 0; p < 4; ++p) br[g][p] = b_s[g * 512 + hid + p];
  const int brow = rows0 + nt * 16 + l15;
  float c4[4] = {0.f, 0.f, 0.f, 0.f};
  const f32x4 z4 = {0.f, 0.f, 0.f, 0.f};
  __syncthreads();   // Ws ready (only barrier in the kernel)

  for (int t = 1; t <= 128; ++t) {
    const size_t gbase = ((size_t)brow * 128 + (t - 1)) * 2048;
    bf16x4v gp[4];
#pragma unroll
    for (int g = 0; g < 4; ++g) gp[g] = *(const bf16x4v*)&gs[gbase + g * 512 + hid];

    f32x4 acc[4];
#pragma unroll
    for (int g = 0; g < 4; ++g) acc[g] = z4;

    if (t >= 2) {
      const unsigned tgt = (unsigned)(t - 1);
      for (;;) {
        unsigned f = tgt;
        if (lane < 32)   // 32 uints within one 256B group -> 1-2 L3 requests
          f = __hip_atomic_load(fgrp + pline, __ATOMIC_RELAXED, __HIP_MEMORY_SCOPE_AGENT);
        if (__all((int)(f >= tgt))) break;
        __builtin_amdgcn_s_sleep(2);
      }
      __asm__ __volatile__("" ::: "memory");
      const u64* hrow = (const u64*)
          (hb + ((size_t)((t & 1) ^ 1) * 256 + brow) * 512);
#pragma unroll
      for (int ks = 0; ks < 16; ++ks) {
        U16 u;
        u.s.a = aload8(hrow + ks * 8 + quad * 2);
        u.s.b = aload8(hrow + ks * 8 + quad * 2 + 1);
#pragma unroll
        for (int g = 0; g < 4; ++g) {
          bf16x8 af = *(const bf16x8*)&Ws[(g * 32 + hb2 * 16 + l15) * 520 + ks * 32 + quad * 8];
          acc[g] = MFMA_BF16(af, u.v, acc[g]);
        }
      }
    }
    bf16x4v hv;
    float hf[4];
#pragma unroll
    for (int p = 0; p < 4; ++p) {
      float Pi = acc[0][p] + (float)gp[0][p] + br[0][p];
      float Pf = acc[1][p] + (float)gp[1][p] + br[1][p];
      float Pg = acc[2][p] + (float)gp[2][p] + br[2][p];
      float Po = acc[3][p] + (float)gp[3][p] + br[3][p];
      float cc = sigm_(Pf) * c4[p] + sigm_(Pi) * tanh_(Pg);
      c4[p] = cc;
      hf[p] = sigm_(Po) * tanh_(cc);
      hv[p] = (bf16_t)hf[p];
    }
    if (t < 128) {
      U8 cv; cv.v = hv;
      astore8((u64*)(hb + ((size_t)(t & 1) * 256 + brow) * 512 + hid), cv.u);
      if (lane == 0)
        __hip_atomic_store(fmine, (unsigned)t, __ATOMIC_RELEASE, __HIP_MEMORY_SCOPE_AGENT);
    } else {
      *(float4*)&hT[(size_t)brow * 512 + hid] = make_float4(hf[0], hf[1], hf[2], hf[3]);
    }
  }
}

// ------------------------------- emissions ---------------------------------
__global__ void emis_k(const float* __restrict__ hT, const float* __restrict__ lin_w,
                       const float* __restrict__ lin_b, float* __restrict__ em) {
  const int idx = blockIdx.x * 256 + threadIdx.x;
  const int s = idx >> 4, c = idx & 15;
  const float4* h4 = (const float4*)(hT + (size_t)s * 512);
  const float4* w4 = (const float4*)(lin_w + (size_t)c * 512);
  float acc = lin_b[c];
  for (int k = 0; k < 128; ++k) {
    float4 a = h4[k], b = w4[k];
    acc += a.x * b.x + a.y * b.y + a.z * b.z + a.w * b.w;
  }
  em[idx] = acc;
}

// ---------------------------------- CRF ------------------------------------
__global__ void crf_k(const float* __restrict__ em, const int* __restrict__ y,
                      const float* __restrict__ cs, const float* __restrict__ ce,
                      const float* __restrict__ tr, float* __restrict__ out) {
  __shared__ float alpha[16];
  __shared__ float trs[256];
  const int lane = threadIdx.x;
  const int i = lane & 15, jg = lane >> 4;

  for (int k = lane; k < 256; k += 64) trs[k] = tr[k];
  __syncthreads();

  float np = 0.f;
  for (int s = lane; s < 256; s += 64) np += em[s * 16 + y[s]];
  for (int s = lane + 1; s < 256; s += 64) np += trs[y[s - 1] * 16 + y[s]];
#pragma unroll
  for (int off = 32; off > 0; off >>= 1) np += __shfl_down(np, off, 64);

  if (lane < 16) alpha[lane] = cs[lane] + em[lane];
  __syncthreads();

  for (int s = 1; s < 256; ++s) {
    const float* e = em + s * 16;
    float v[4];
#pragma unroll
    for (int jj = 0; jj < 4; ++jj) v[jj] = alpha[i] + trs[i * 16 + (jj * 4 + jg)];
    float res[4];
#pragma unroll
    for (int jj = 0; jj < 4; ++jj) {
      float m = v[jj];
      m = fmaxf(m, __shfl_xor(m, 1, 64));
      m = fmaxf(m, __shfl_xor(m, 2, 64));
      m = fmaxf(m, __shfl_xor(m, 4, 64));
      m = fmaxf(m, __shfl_xor(m, 8, 64));
      float ex = __expf(v[jj] - m);
      ex += __shfl_xor(ex, 1, 64);
      ex += __shfl_xor(ex, 2, 64);
      ex += __shfl_xor(ex, 4, 64);
      ex += __shfl_xor(ex, 8, 64);
      res[jj] = m + __logf(ex) + e[jj * 4 + jg];
    }
#pragma unroll
    for (int jj = 0; jj < 4; ++jj)
      if (i == 0) alpha[jj * 4 + jg] = res[jj];
  }

  float v = (lane < 16) ? (alpha[lane] + ce[lane]) : -3.0e38f;
  float m = v;
#pragma unroll
  for (int off = 32; off > 0; off >>= 1) m = fmaxf(m, __shfl_xor(m, off, 64));
  float ex = __expf(v - m);
#pragma unroll
  for (int off = 32; off > 0; off >>= 1) ex += __shfl_xor(ex, off, 64);
  float denom = m + __logf(ex);

  if (lane == 0) {
    float num = np + cs[y[0]] + ce[y[255]];
    out[0] = num - denom;
  }
}

// ------------------------------ orchestration ------------------------------
extern "C" void kernel_launch(void* const* d_in, const int* in_sizes, int n_in,
                              void* d_out, int out_size, void* d_ws, size_t ws_size,
                              hipStream_t stream) {
  const float* x = (const float*)d_in[0];
  const int* y = (const int*)d_in[1];
  const float* w_ih_f = (const float*)d_in[3];
  const float* w_hh_f = (const float*)d_in[4];
  const float* b_f = (const float*)d_in[5];
  const float* w_ih_r = (const float*)d_in[6];
  const float* w_hh_r = (const float*)d_in[7];
  const float* b_r = (const float*)d_in[8];
  const float* w_ih_s = (const float*)d_in[9];
  const float* w_hh_s = (const float*)d_in[10];
  const float* b_s = (const float*)d_in[11];
  const float* lin_w = (const float*)d_in[12];
  const float* lin_b = (const float*)d_in[13];
  const float* crf_s = (const float*)d_in[14];
  const float* crf_e = (const float*)d_in[15];
  const float* crf_t = (const float*)d_in[16];

  char* ws = (char*)d_ws;
  size_t off = 0;
  auto take = [&](size_t bytes) {
    void* p = ws + off;
    off += (bytes + 255) & ~(size_t)255;
    return p;
  };
  bf16_t* Wx  = (bf16_t*)take((size_t)2048 * 768 * 2);
  bf16_t* Whh = (bf16_t*)take((size_t)2 * 1024 * 256 * 2);
  bf16_t* Wsi = (bf16_t*)take((size_t)2048 * 512 * 2);
  bf16_t* Wsh = (bf16_t*)take((size_t)2048 * 512 * 2);
  bf16_t* gx  = (bf16_t*)take((size_t)32768 * 2048 * 2);
  bf16_t* xb  = (bf16_t*)take((size_t)32768 * 768 * 2);   // 48MB region
  float* hT   = (float*)take((size_t)256 * 512 * 4);
  float* em   = (float*)take((size_t)4096 * 4);
  bf16_t* gs = gx;       // gx dead after lstm_fr
  bf16_t* hcat = xb;     // xb dead after gemm1; h_cat uses [0,32MB)
  char* tail = (char*)xb + 33554432;
  bf16_t* hb_fr = (bf16_t*)tail;                    // 2par x 2dir x 256 x 256 x 2B = 512KB
  bf16_t* hb_s  = (bf16_t*)(tail + 524288);         // 2par x 256 x 512 x 2B       = 512KB
  unsigned* flags_fr = (unsigned*)(tail + 1048576); // 32 grp x 32 uints = 4KB
  unsigned* flags_s  = flags_fr + 1024;             // 8 grp x 64 uints  = 2KB
  (void)ws_size; (void)in_sizes; (void)n_in; (void)out_size;

  // phase 1: converts
  cvt4<<<2048, 256, 0, stream>>>(x, xb, 32768 * 768 / 4);
  cvt4<<<64, 256, 0, stream>>>(w_ih_f, Wx, 786432 / 4);
  cvt4<<<64, 256, 0, stream>>>(w_ih_r, Wx + 786432, 786432 / 4);
  cvt4<<<32, 256, 0, stream>>>(w_hh_f, Whh, 262144 / 4);
  cvt4<<<32, 256, 0, stream>>>(w_hh_r, Whh + 262144, 262144 / 4);
  cvt4<<<64, 256, 0, stream>>>(w_ih_s, Wsi, 1048576 / 4);
  cvt4<<<64, 256, 0, stream>>>(w_hh_s, Wsh, 1048576 / 4);

  // phase 2: input gates for fwd+rev   (M=32768, N=2048, K=768)
  gemm_bt<<<4096, 256, 0, stream>>>(xb, Wx, gx, 32768, 2048, 768);

  // flags live in xb tail — zero only after gemm1 is done with xb
  // (both arrays: 1024+512 uints = 768 u64)
  zero8<<<8, 256, 0, stream>>>((u64*)flags_fr, 768);

  // phase 3: fwd/rev recurrences -> h_cat
  lstm_fr<<<128, 256, 0, stream>>>(gx, Whh, b_f, b_r, hcat, hb_fr, flags_fr);

  // phase 4: sentence input gates     (M=32768, N=2048, K=512)
  gemm_bt<<<4096, 256, 0, stream>>>(hcat, Wsi, gs, 32768, 2048, 512);

  // phase 5: sentence recurrence -> hT
  lstm_s<<<128, 256, 0, stream>>>(gs, Wsh, b_s, hT, hb_s, flags_s);

  // phase 6: emissions + CRF
  emis_k<<<16, 256, 0, stream>>>(hT, lin_w, lin_b, em);
  crf_k<<<1, 64, 0, stream>>>(em, y, crf_s, crf_e, crf_t, (float*)d_out);
}

// Round 6
// 3040.973 us; speedup vs baseline: 1.5621x; 1.5621x over previous
//
#include <hip/hip_runtime.h>
#include <hip/hip_bf16.h>
#include <stdint.h>

// ---------------------------------------------------------------------------
// BiLSTM (H=256, fwd+rev) -> sentence LSTM (512->512) -> linear -> CRF(16)
// Round 12: hint-flag + tag-in-data hybrid.
//   Correctness from tags, latency from hints:
//   - hb word = {2 x bf16 payload, u32 step tag} stored with ONE relaxed
//     agent-scope 8B atomic -> single-copy atomic, no ordering needed.
//   - Producer: fire h-word stores, then tid0 fires a per-block HINT flag
//     (relaxed, NOT release) -> no vmcnt drain anywhere in the step loop.
//     Only raw s_barrier (no waitcnt) keeps waves lockstep.
//   - Consumer: wave0 polls the group's hint lines (R0's proven per-block
//     128B-line layout), raw-barrier broadcast, then loads h ONCE and
//     verifies tags; stale chunks re-loaded via a miss-mask with s_sleep(1)
//     backoff. Hints make pass-1 clean (no R1/R3 retry storm); tags make
//     hints advisory (no R0 drain).
//   - Overwrite safety (2-parity): producer at t+1 verified tags(t) from all
//     peers => peers finished reading h(t-1) => overwriting parity (t+1)&1
//     is safe. Tags also catch any straggler.
//   - Spill control: lstm_s drains K in two 8-chunk batches (wv = 64 VGPR,
//     statically indexed); lstm_fr is one 8-chunk batch.
//   - MFMA ks-order and operand bytes bit-identical to R0 -> absmax 0.0.
// ---------------------------------------------------------------------------

typedef __bf16 bf16_t;
typedef __bf16 bf16x8 __attribute__((ext_vector_type(8)));
typedef __bf16 bf16x4v __attribute__((ext_vector_type(4)));
typedef float f32x4 __attribute__((ext_vector_type(4)));
typedef unsigned long long u64;

#define MFMA_BF16(a, b, c) __builtin_amdgcn_mfma_f32_16x16x32_bf16((a), (b), (c), 0, 0, 0)

__device__ __forceinline__ float sigm_(float x) { return 1.f / (1.f + __expf(-x)); }
__device__ __forceinline__ float tanh_(float x) {
  x = fminf(20.f, fmaxf(-20.f, x));
  float e = __expf(-2.f * x);
  return (1.f - e) / (1.f + e);
}

__device__ __forceinline__ u64 aload8(const u64* p) {
  return __hip_atomic_load(p, __ATOMIC_RELAXED, __HIP_MEMORY_SCOPE_AGENT);
}
__device__ __forceinline__ void astore8(u64* p, u64 v) {
  __hip_atomic_store(p, v, __ATOMIC_RELAXED, __HIP_MEMORY_SCOPE_AGENT);
}

union U8 { bf16x4v v; uint2 u; };           // pack 4 bf16 -> 2 dwords
union B8 { uint32_t u[4]; bf16x8 v; };      // 4 payload dwords -> MFMA B frag

// zero hb+flags each launch (stale tags would otherwise satisfy tag checks)
__global__ void zero8(u64* __restrict__ p, int n) {
  int i = blockIdx.x * 256 + threadIdx.x;
  int s = gridDim.x * 256;
  for (; i < n; i += s) p[i] = 0ull;
}

// ---------------------------- fp32 -> bf16 convert -------------------------
__global__ void cvt4(const float* __restrict__ in, bf16_t* __restrict__ out, int n4) {
  int i = blockIdx.x * blockDim.x + threadIdx.x;
  int stride = gridDim.x * blockDim.x;
  for (; i < n4; i += stride) {
    float4 v = ((const float4*)in)[i];
    bf16x4v o;
    o.x = (bf16_t)v.x; o.y = (bf16_t)v.y; o.z = (bf16_t)v.z; o.w = (bf16_t)v.w;
    ((bf16x4v*)out)[i] = o;
  }
}

// ------------------------------- bf16 GEMM ---------------------------------
__global__ void __launch_bounds__(256, 2)
gemm_bt(const bf16_t* __restrict__ A, const bf16_t* __restrict__ B,
        bf16_t* __restrict__ C, int M, int N, int K) {
  const int tid = threadIdx.x;
  const int w = tid >> 6, lane = tid & 63, quad = lane >> 4, l15 = lane & 15;
  const int ntiles = N >> 7;
  const int m0 = (blockIdx.x / ntiles) << 7;
  const int n0 = (blockIdx.x % ntiles) << 7;
  const int wm = (w >> 1) << 6, wn = (w & 1) << 6;

  __shared__ bf16_t As[128 * 72];
  __shared__ bf16_t Bs[128 * 72];

  const f32x4 z4 = {0.f, 0.f, 0.f, 0.f};
  f32x4 acc[4][4];
#pragma unroll
  for (int i = 0; i < 4; ++i)
#pragma unroll
    for (int j = 0; j < 4; ++j) acc[i][j] = z4;

  const int nk = K >> 6;
  for (int kt = 0; kt < nk; ++kt) {
    uint4 av[4], bv[4];
#pragma unroll
    for (int i = 0; i < 4; ++i) {
      int cid = tid + i * 256;
      int r = cid >> 3, c = cid & 7;
      av[i] = *(const uint4*)&A[(size_t)(m0 + r) * K + kt * 64 + c * 8];
      bv[i] = *(const uint4*)&B[(size_t)(n0 + r) * K + kt * 64 + c * 8];
    }
    __syncthreads();
#pragma unroll
    for (int i = 0; i < 4; ++i) {
      int cid = tid + i * 256;
      int r = cid >> 3, c = cid & 7;
      *(uint4*)&As[r * 72 + c * 8] = av[i];
      *(uint4*)&Bs[r * 72 + c * 8] = bv[i];
    }
    __syncthreads();
#pragma unroll
    for (int s = 0; s < 2; ++s) {
      bf16x8 af[4], bfr[4];
#pragma unroll
      for (int i = 0; i < 4; ++i)
        af[i] = *(const bf16x8*)&As[(wm + i * 16 + l15) * 72 + s * 32 + quad * 8];
#pragma unroll
      for (int j = 0; j < 4; ++j)
        bfr[j] = *(const bf16x8*)&Bs[(wn + j * 16 + l15) * 72 + s * 32 + quad * 8];
#pragma unroll
      for (int i = 0; i < 4; ++i)
#pragma unroll
        for (int j = 0; j < 4; ++j)
          acc[i][j] = MFMA_BF16(af[i], bfr[j], acc[i][j]);
    }
  }
#pragma unroll
  for (int i = 0; i < 4; ++i)
#pragma unroll
    for (int j = 0; j < 4; ++j)
#pragma unroll
      for (int p = 0; p < 4; ++p) {
        int row = m0 + wm + i * 16 + quad * 4 + p;
        int col = n0 + wn + j * 16 + l15;
        C[(size_t)row * N + col] = (bf16_t)acc[i][j][p];
      }
}

// ----------------------- fwd/rev LSTM recurrence ---------------------------
// 128 blocks. grp = blockIdx&31 (dir*16+bg), hsp = blockIdx>>5 — group
// members share blockIdx%8 (XCD co-location heuristic; correctness-neutral).
// Hints: flags[grp*128 + hsp*32] — per-block, own 128B line, stored by tid0
// RELAXED (no drain). hb: [par(2)][dir(2)][256 rows][128 words] tagged.
__global__ void __launch_bounds__(256, 1)
lstm_fr(const bf16_t* __restrict__ gx, const bf16_t* __restrict__ whh,
        const float* __restrict__ b_f, const float* __restrict__ b_r,
        bf16_t* __restrict__ h_cat, u64* __restrict__ hb,
        unsigned* __restrict__ flags) {
  const int tid = threadIdx.x;
  const int w = tid >> 6, lane = tid & 63, quad = lane >> 4, l15 = lane & 15;
  const int grp = blockIdx.x & 31;
  const int hsp = blockIdx.x >> 5;
  const int dir = grp >> 4;
  const int bg = grp & 15;
  const int rows0 = bg << 4;
  const int hid0 = hsp << 6;
  unsigned* fgrp = flags + grp * 128;       // 4 lines x 32 uints
  unsigned* fmine = fgrp + hsp * 32;

  __shared__ bf16_t Ws[256 * 264];   // packed row = g*64+hh, K=256 (+8 pad)
  const bf16_t* Wg = whh + (size_t)dir * 262144;
#pragma unroll
  for (int i = 0; i < 32; ++i) {
    int id = tid + i * 256;          // 8192 = 256 rows x 32 chunks(16B)
    int r = id >> 5, c = id & 31;
    int g = r >> 6, hh = r & 63;
    *(uint4*)&Ws[r * 264 + c * 8] =
        *(const uint4*)&Wg[(size_t)(g * 256 + hid0 + hh) * 256 + c * 8];
  }
  const float* bias = dir ? b_r : b_f;
  const int hid = hid0 + w * 16 + quad * 4;   // 4 consecutive hid per lane
  float br[4][4];
#pragma unroll
  for (int g = 0; g < 4; ++g)
#pragma unroll
    for (int p = 0; p < 4; ++p) br[g][p] = bias[g * 256 + hid + p];
  const int brow = rows0 + l15;
  float c4[4] = {0.f, 0.f, 0.f, 0.f};
  const f32x4 z4 = {0.f, 0.f, 0.f, 0.f};
  __syncthreads();   // Ws ready

  for (int t = 1; t <= 128; ++t) {
    const int tt = dir ? (128 - t) : (t - 1);
    // gate prefetch — issued before the poll, overlaps the wait
    const size_t gbase = ((size_t)brow * 128 + tt) * 2048 + (size_t)dir * 1024;
    bf16x4v gp[4];
#pragma unroll
    for (int g = 0; g < 4; ++g) gp[g] = *(const bf16x4v*)&gx[gbase + g * 256 + hid];

    f32x4 acc[4];
#pragma unroll
    for (int g = 0; g < 4; ++g) acc[g] = z4;

    if (t >= 2) {
      const unsigned tgt = (unsigned)(t - 1);
      if (w == 0) {   // wave0 polls the 4 hint lines
        for (;;) {
          unsigned f = tgt;
          if (lane < 4)
            f = __hip_atomic_load(fgrp + lane * 32, __ATOMIC_RELAXED, __HIP_MEMORY_SCOPE_AGENT);
          if (__all((int)(f >= tgt))) break;
          __builtin_amdgcn_s_sleep(1);
        }
      }
      __builtin_amdgcn_s_barrier();          // raw: broadcast, no vmcnt drain
      __asm__ __volatile__("" ::: "memory");

      const u64* hrow = hb + (((size_t)((t & 1) ^ 1) * 2 + dir) * 256 + brow) * 128;
      u64 wv[8][4];
#pragma unroll
      for (int ks = 0; ks < 8; ++ks)
#pragma unroll
        for (int p = 0; p < 4; ++p)
          wv[ks][p] = aload8(hrow + ks * 16 + quad * 4 + p);
      unsigned miss = 0;
#pragma unroll
      for (int ks = 0; ks < 8; ++ks) {
        bool ok = ((unsigned)(wv[ks][0] >> 32) == tgt) &&
                  ((unsigned)(wv[ks][1] >> 32) == tgt) &&
                  ((unsigned)(wv[ks][2] >> 32) == tgt) &&
                  ((unsigned)(wv[ks][3] >> 32) == tgt);
        if (!__all((int)ok)) miss |= 1u << ks;
      }
      while (miss) {
        __builtin_amdgcn_s_sleep(1);
#pragma unroll
        for (int ks = 0; ks < 8; ++ks)
          if (miss & (1u << ks)) {
#pragma unroll
            for (int p = 0; p < 4; ++p)
              wv[ks][p] = aload8(hrow + ks * 16 + quad * 4 + p);
            bool ok = ((unsigned)(wv[ks][0] >> 32) == tgt) &&
                      ((unsigned)(wv[ks][1] >> 32) == tgt) &&
                      ((unsigned)(wv[ks][2] >> 32) == tgt) &&
                      ((unsigned)(wv[ks][3] >> 32) == tgt);
            if (__all((int)ok)) miss &= ~(1u << ks);
          }
      }
      __asm__ __volatile__("" ::: "memory");
#pragma unroll
      for (int ks = 0; ks < 8; ++ks) {
        B8 Bv;
#pragma unroll
        for (int p = 0; p < 4; ++p) Bv.u[p] = (uint32_t)wv[ks][p];
#pragma unroll
        for (int g = 0; g < 4; ++g) {
          bf16x8 af = *(const bf16x8*)&Ws[(g * 64 + w * 16 + l15) * 264 + ks * 32 + quad * 8];
          acc[g] = MFMA_BF16(af, Bv.v, acc[g]);
        }
      }
    }
    // epilogue: lane holds all 4 gates for (batch=brow, hid..hid+3)
    bf16x4v hv;
#pragma unroll
    for (int p = 0; p < 4; ++p) {
      float Pi = acc[0][p] + (float)gp[0][p] + br[0][p];
      float Pf = acc[1][p] + (float)gp[1][p] + br[1][p];
      float Pg = acc[2][p] + (float)gp[2][p] + br[2][p];
      float Po = acc[3][p] + (float)gp[3][p] + br[3][p];
      float cc = sigm_(Pf) * c4[p] + sigm_(Pi) * tanh_(Pg);
      c4[p] = cc;
      hv[p] = (bf16_t)(sigm_(Po) * tanh_(cc));
    }
    if (t < 128) {
      U8 cv; cv.v = hv;
      const u64 tag = (u64)(unsigned)t << 32;
      u64* orow = hb + (((size_t)(t & 1) * 2 + dir) * 256 + brow) * 128 + (hid >> 1);
      astore8(orow,     (u64)cv.u.x | tag);
      astore8(orow + 1, (u64)cv.u.y | tag);
      if (tid == 0)   // HINT: relaxed, fire-and-forget (tags are the truth)
        __hip_atomic_store(fmine, (unsigned)t, __ATOMIC_RELAXED, __HIP_MEMORY_SCOPE_AGENT);
    }
    // h_cat store — fire-and-forget, never drained
    *(bf16x4v*)&h_cat[((size_t)brow * 128 + tt) * 512 + dir * 256 + hid] = hv;
  }
}

// ------------------------ sentence LSTM recurrence -------------------------
// 128 blocks. bg = blockIdx&7 (XCD co-location), hsp = blockIdx>>3.
// Hints: flags[bg*512 + hsp*32] — per-block 128B lines, tid0 relaxed store.
// hb: [par(2)][256 rows][256 words] tagged. K drained in two 8-chunk batches.
__global__ void __launch_bounds__(256, 1)
lstm_s(const bf16_t* __restrict__ gs, const bf16_t* __restrict__ wsh,
       const float* __restrict__ b_s, float* __restrict__ hT,
       u64* __restrict__ hb, unsigned* __restrict__ flags) {
  const int tid = threadIdx.x;
  const int w = tid >> 6, lane = tid & 63, quad = lane >> 4, l15 = lane & 15;
  const int bg = blockIdx.x & 7;
  const int hsp = blockIdx.x >> 3;
  const int rows0 = bg << 5;
  const int hid0 = hsp << 5;
  const int nt = w & 1, hb2 = w >> 1;         // wave: batch-half, hid-half
  unsigned* fgrp = flags + bg * 512;          // 16 lines x 32 uints
  unsigned* fmine = fgrp + hsp * 32;

  __shared__ bf16_t Ws[128 * 520];   // packed row = g*32+hh, K=512 (+8 pad)
#pragma unroll
  for (int i = 0; i < 32; ++i) {
    int id = tid + i * 256;          // 8192 = 128 rows x 64 chunks(16B)
    int r = id >> 6, c = id & 63;
    int g = r >> 5, hh = r & 31;
    *(uint4*)&Ws[r * 520 + c * 8] =
        *(const uint4*)&wsh[(size_t)(g * 512 + hid0 + hh) * 512 + c * 8];
  }
  const int hid = hid0 + hb2 * 16 + quad * 4;
  float br[4][4];
#pragma unroll
  for (int g = 0; g < 4; ++g)
#pragma unroll
    for (int p = 0; p < 4; ++p) br[g][p] = b_s[g * 512 + hid + p];
  const int brow = rows0 + nt * 16 + l15;
  float c4[4] = {0.f, 0.f, 0.f, 0.f};
  const f32x4 z4 = {0.f, 0.f, 0.f, 0.f};
  __syncthreads();   // Ws ready

  for (int t = 1; t <= 128; ++t) {
    const size_t gbase = ((size_t)brow * 128 + (t - 1)) * 2048;
    bf16x4v gp[4];
#pragma unroll
    for (int g = 0; g < 4; ++g) gp[g] = *(const bf16x4v*)&gs[gbase + g * 512 + hid];

    f32x4 acc[4];
#pragma unroll
    for (int g = 0; g < 4; ++g) acc[g] = z4;

    if (t >= 2) {
      const unsigned tgt = (unsigned)(t - 1);
      if (w == 0) {   // wave0 polls the 16 hint lines
        for (;;) {
          unsigned f = tgt;
          if (lane < 16)
            f = __hip_atomic_load(fgrp + lane * 32, __ATOMIC_RELAXED, __HIP_MEMORY_SCOPE_AGENT);
          if (__all((int)(f >= tgt))) break;
          __builtin_amdgcn_s_sleep(1);
        }
      }
      __builtin_amdgcn_s_barrier();          // raw: broadcast, no vmcnt drain
      __asm__ __volatile__("" ::: "memory");

      const u64* hrow = hb + ((size_t)((t & 1) ^ 1) * 256 + brow) * 256;
#pragma unroll
      for (int kb = 0; kb < 2; ++kb) {       // two 8-chunk batches (VGPR cap)
        u64 wv[8][4];
#pragma unroll
        for (int i = 0; i < 8; ++i)
#pragma unroll
          for (int p = 0; p < 4; ++p)
            wv[i][p] = aload8(hrow + (kb * 8 + i) * 16 + quad * 4 + p);
        unsigned miss = 0;
#pragma unroll
        for (int i = 0; i < 8; ++i) {
          bool ok = ((unsigned)(wv[i][0] >> 32) == tgt) &&
                    ((unsigned)(wv[i][1] >> 32) == tgt) &&
                    ((unsigned)(wv[i][2] >> 32) == tgt) &&
                    ((unsigned)(wv[i][3] >> 32) == tgt);
          if (!__all((int)ok)) miss |= 1u << i;
        }
        while (miss) {
          __builtin_amdgcn_s_sleep(1);
#pragma unroll
          for (int i = 0; i < 8; ++i)
            if (miss & (1u << i)) {
#pragma unroll
              for (int p = 0; p < 4; ++p)
                wv[i][p] = aload8(hrow + (kb * 8 + i) * 16 + quad * 4 + p);
              bool ok = ((unsigned)(wv[i][0] >> 32) == tgt) &&
                        ((unsigned)(wv[i][1] >> 32) == tgt) &&
                        ((unsigned)(wv[i][2] >> 32) == tgt) &&
                        ((unsigned)(wv[i][3] >> 32) == tgt);
              if (__all((int)ok)) miss &= ~(1u << i);
            }
        }
        __asm__ __volatile__("" ::: "memory");
#pragma unroll
        for (int i = 0; i < 8; ++i) {
          const int ks = kb * 8 + i;
          B8 Bv;
#pragma unroll
          for (int p = 0; p < 4; ++p) Bv.u[p] = (uint32_t)wv[i][p];
#pragma unroll
          for (int g = 0; g < 4; ++g) {
            bf16x8 af = *(const bf16x8*)&Ws[(g * 32 + hb2 * 16 + l15) * 520 + ks * 32 + quad * 8];
            acc[g] = MFMA_BF16(af, Bv.v, acc[g]);
          }
        }
      }
    }
    bf16x4v hv;
    float hf[4];
#pragma unroll
    for (int p = 0; p < 4; ++p) {
      float Pi = acc[0][p] + (float)gp[0][p] + br[0][p];
      float Pf = acc[1][p] + (float)gp[1][p] + br[1][p];
      float Pg = acc[2][p] + (float)gp[2][p] + br[2][p];
      float Po = acc[3][p] + (float)gp[3][p] + br[3][p];
      float cc = sigm_(Pf) * c4[p] + sigm_(Pi) * tanh_(Pg);
      c4[p] = cc;
      hf[p] = sigm_(Po) * tanh_(cc);
      hv[p] = (bf16_t)hf[p];
    }
    if (t < 128) {
      U8 cv; cv.v = hv;
      const u64 tag = (u64)(unsigned)t << 32;
      u64* orow = hb + ((size_t)(t & 1) * 256 + brow) * 256 + (hid >> 1);
      astore8(orow,     (u64)cv.u.x | tag);
      astore8(orow + 1, (u64)cv.u.y | tag);
      if (tid == 0)
        __hip_atomic_store(fmine, (unsigned)t, __ATOMIC_RELAXED, __HIP_MEMORY_SCOPE_AGENT);
    } else {
      *(float4*)&hT[(size_t)brow * 512 + hid] = make_float4(hf[0], hf[1], hf[2], hf[3]);
    }
  }
}

// ------------------------------- emissions ---------------------------------
__global__ void emis_k(const float* __restrict__ hT, const float* __restrict__ lin_w,
                       const float* __restrict__ lin_b, float* __restrict__ em) {
  const int idx = blockIdx.x * 256 + threadIdx.x;
  const int s = idx >> 4, c = idx & 15;
  const float4* h4 = (const float4*)(hT + (size_t)s * 512);
  const float4* w4 = (const float4*)(lin_w + (size_t)c * 512);
  float acc = lin_b[c];
  for (int k = 0; k < 128; ++k) {
    float4 a = h4[k], b = w4[k];
    acc += a.x * b.x + a.y * b.y + a.z * b.z + a.w * b.w;
  }
  em[idx] = acc;
}

// ---------------------------------- CRF ------------------------------------
__global__ void crf_k(const float* __restrict__ em, const int* __restrict__ y,
                      const float* __restrict__ cs, const float* __restrict__ ce,
                      const float* __restrict__ tr, float* __restrict__ out) {
  __shared__ float alpha[16];
  __shared__ float trs[256];
  const int lane = threadIdx.x;
  const int i = lane & 15, jg = lane >> 4;

  for (int k = lane; k < 256; k += 64) trs[k] = tr[k];
  __syncthreads();

  float np = 0.f;
  for (int s = lane; s < 256; s += 64) np += em[s * 16 + y[s]];
  for (int s = lane + 1; s < 256; s += 64) np += trs[y[s - 1] * 16 + y[s]];
#pragma unroll
  for (int off = 32; off > 0; off >>= 1) np += __shfl_down(np, off, 64);

  if (lane < 16) alpha[lane] = cs[lane] + em[lane];
  __syncthreads();

  for (int s = 1; s < 256; ++s) {
    const float* e = em + s * 16;
    float v[4];
#pragma unroll
    for (int jj = 0; jj < 4; ++jj) v[jj] = alpha[i] + trs[i * 16 + (jj * 4 + jg)];
    float res[4];
#pragma unroll
    for (int jj = 0; jj < 4; ++jj) {
      float m = v[jj];
      m = fmaxf(m, __shfl_xor(m, 1, 64));
      m = fmaxf(m, __shfl_xor(m, 2, 64));
      m = fmaxf(m, __shfl_xor(m, 4, 64));
      m = fmaxf(m, __shfl_xor(m, 8, 64));
      float ex = __expf(v[jj] - m);
      ex += __shfl_xor(ex, 1, 64);
      ex += __shfl_xor(ex, 2, 64);
      ex += __shfl_xor(ex, 4, 64);
      ex += __shfl_xor(ex, 8, 64);
      res[jj] = m + __logf(ex) + e[jj * 4 + jg];
    }
#pragma unroll
    for (int jj = 0; jj < 4; ++jj)
      if (i == 0) alpha[jj * 4 + jg] = res[jj];
  }

  float v = (lane < 16) ? (alpha[lane] + ce[lane]) : -3.0e38f;
  float m = v;
#pragma unroll
  for (int off = 32; off > 0; off >>= 1) m = fmaxf(m, __shfl_xor(m, off, 64));
  float ex = __expf(v - m);
#pragma unroll
  for (int off = 32; off > 0; off >>= 1) ex += __shfl_xor(ex, off, 64);
  float denom = m + __logf(ex);

  if (lane == 0) {
    float num = np + cs[y[0]] + ce[y[255]];
    out[0] = num - denom;
  }
}

// ------------------------------ orchestration ------------------------------
extern "C" void kernel_launch(void* const* d_in, const int* in_sizes, int n_in,
                              void* d_out, int out_size, void* d_ws, size_t ws_size,
                              hipStream_t stream) {
  const float* x = (const float*)d_in[0];
  const int* y = (const int*)d_in[1];
  const float* w_ih_f = (const float*)d_in[3];
  const float* w_hh_f = (const float*)d_in[4];
  const float* b_f = (const float*)d_in[5];
  const float* w_ih_r = (const float*)d_in[6];
  const float* w_hh_r = (const float*)d_in[7];
  const float* b_r = (const float*)d_in[8];
  const float* w_ih_s = (const float*)d_in[9];
  const float* w_hh_s = (const float*)d_in[10];
  const float* b_s = (const float*)d_in[11];
  const float* lin_w = (const float*)d_in[12];
  const float* lin_b = (const float*)d_in[13];
  const float* crf_s = (const float*)d_in[14];
  const float* crf_e = (const float*)d_in[15];
  const float* crf_t = (const float*)d_in[16];

  char* ws = (char*)d_ws;
  size_t off = 0;
  auto take = [&](size_t bytes) {
    void* p = ws + off;
    off += (bytes + 255) & ~(size_t)255;
    return p;
  };
  bf16_t* Wx  = (bf16_t*)take((size_t)2048 * 768 * 2);
  bf16_t* Whh = (bf16_t*)take((size_t)2 * 1024 * 256 * 2);
  bf16_t* Wsi = (bf16_t*)take((size_t)2048 * 512 * 2);
  bf16_t* Wsh = (bf16_t*)take((size_t)2048 * 512 * 2);
  bf16_t* gx  = (bf16_t*)take((size_t)32768 * 2048 * 2);
  bf16_t* xb  = (bf16_t*)take((size_t)32768 * 768 * 2);   // 48MB region
  float* hT   = (float*)take((size_t)256 * 512 * 4);
  float* em   = (float*)take((size_t)4096 * 4);
  bf16_t* gs = gx;       // gx dead after lstm_fr
  bf16_t* hcat = xb;     // xb dead after gemm1; h_cat uses [0,32MB)
  char* tail = (char*)xb + 33554432;
  u64* hb_fr = (u64*)tail;                          // 2par x 2dir x 256 x 128 x 8B = 1MB
  u64* hb_s  = (u64*)(tail + 1048576);              // 2par x 256 x 256 x 8B       = 1MB
  unsigned* flags_fr = (unsigned*)(tail + 2097152); // 32 grp x 4 lines x 32 = 16KB
  unsigned* flags_s  = flags_fr + 4096;             // 8 grp x 16 lines x 32 = 16KB
  (void)ws_size; (void)in_sizes; (void)n_in; (void)out_size;

  // phase 1: converts
  cvt4<<<2048, 256, 0, stream>>>(x, xb, 32768 * 768 / 4);
  cvt4<<<64, 256, 0, stream>>>(w_ih_f, Wx, 786432 / 4);
  cvt4<<<64, 256, 0, stream>>>(w_ih_r, Wx + 786432, 786432 / 4);
  cvt4<<<32, 256, 0, stream>>>(w_hh_f, Whh, 262144 / 4);
  cvt4<<<32, 256, 0, stream>>>(w_hh_r, Whh + 262144, 262144 / 4);
  cvt4<<<64, 256, 0, stream>>>(w_ih_s, Wsi, 1048576 / 4);
  cvt4<<<64, 256, 0, stream>>>(w_hh_s, Wsh, 1048576 / 4);

  // phase 2: input gates for fwd+rev   (M=32768, N=2048, K=768)
  gemm_bt<<<4096, 256, 0, stream>>>(xb, Wx, gx, 32768, 2048, 768);

  // hb+flags live in xb tail — zero only after gemm1 is done with xb
  // (2MB hb = 262144 u64, +32KB flags = 4096 u64)
  zero8<<<512, 256, 0, stream>>>(hb_fr, 266240);

  // phase 3: fwd/rev recurrences -> h_cat
  lstm_fr<<<128, 256, 0, stream>>>(gx, Whh, b_f, b_r, hcat, hb_fr, flags_fr);

  // phase 4: sentence input gates     (M=32768, N=2048, K=512)
  gemm_bt<<<4096, 256, 0, stream>>>(hcat, Wsi, gs, 32768, 2048, 512);

  // phase 5: sentence recurrence -> hT
  lstm_s<<<128, 256, 0, stream>>>(gs, Wsh, b_s, hT, hb_s, flags_s);

  // phase 6: emissions + CRF
  emis_k<<<16, 256, 0, stream>>>(hT, lin_w, lin_b, em);
  crf_k<<<1, 64, 0, stream>>>(em, y, crf_s, crf_e, crf_t, (float*)d_out);
}